// Round 19
// baseline (251.771 us; speedup 1.0000x reference)
//
#include <hip/hip_runtime.h>
#include <hip/hip_bf16.h>

#define N_NODES 20000
#define NP 20032                 // padded rows (multiple of 64)
#define N_REL 32
#define HID 128
#define EMB 16
#define N_EDGES 600000
#define NB (N_NODES * N_REL)     // 640000 real bins
#define NBP (NP * N_REL)         // 641024 padded bins (pad bins: cnt=0, inv=0)

typedef __attribute__((ext_vector_type(8))) short  bf8v;   // 8 bf16 (MFMA A/B frag)
typedef __attribute__((ext_vector_type(8))) unsigned short us8v; // 16-byte unit
typedef __attribute__((ext_vector_type(4))) unsigned short us4v; // 8-byte unit
typedef __attribute__((ext_vector_type(4))) float  f4v;    // MFMA C/D frag

__device__ __forceinline__ unsigned short f2b(float f) {
    __hip_bfloat16 h = __float2bfloat16(f);
    return __builtin_bit_cast(unsigned short, h);
}
__device__ __forceinline__ float b2f(unsigned short u) {
    unsigned int x = ((unsigned int)u) << 16;
    return __builtin_bit_cast(float, x);
}

// Barrier with LDS-only drain (global prefetches stay in flight).
__device__ __forceinline__ void lds_barrier() {
    asm volatile("s_waitcnt lgkmcnt(0)\n\ts_barrier" ::: "memory");
}

// ======== pre-pass: histogram + fragment-major bf16 weight layouts ========
// Weight layout (fragment-major): B[r][ct8][ks][m16][q][j8] — a wave's
// fragment load (lanes (q,m16)) covers one CONTIGUOUS 1 KB block.
#define R_W2 (N_REL * HID * HID)        // 1048576
#define R_XB (N_NODES * 32)             // 640000
#define R_W1 (N_REL * HID * 32)         // 131072
#define R_R1 (HID * 32)                 // 4096
#define R_R2 (HID * HID)                // 16384
#define R_HIST N_EDGES                  // 600000
#define PRE_TOT (R_W2 + R_XB + R_W1 + R_R1 + R_R2 + R_HIST)

__global__ __launch_bounds__(256) void pre1_k(
    const int* __restrict__ dst, const int* __restrict__ et,
    const float* __restrict__ x, const float* __restrict__ W1,
    const float* __restrict__ root1, const float* __restrict__ W2,
    const float* __restrict__ root2,
    int* __restrict__ hist,
    unsigned short* __restrict__ xb, unsigned short* __restrict__ w1t,
    unsigned short* __restrict__ r1t, unsigned short* __restrict__ w2t,
    unsigned short* __restrict__ r2t) {
    int i = blockIdx.x * 256 + threadIdx.x;
    if (i < R_W2) {
        // coalesced read of W2 [r][k][n]; fragment-major write (KT=4)
        int r = i >> 14, k = (i >> 7) & 127, n = i & 127;
        int ct8 = n >> 4, m16 = n & 15, ks = k >> 5, q = (k >> 3) & 3, j = k & 7;
        w2t[(size_t)r * 16384 + (ct8 * 4 + ks) * 512 + m16 * 32 + q * 8 + j] = f2b(W2[i]);
        return;
    }
    i -= R_W2;
    if (i < R_XB) {
        int n = i >> 5, k = i & 31;
        xb[i] = (k < EMB) ? f2b(x[n * EMB + k]) : (unsigned short)0;
        return;
    }
    i -= R_XB;
    if (i < R_W1) {
        // dst-linear fragment-major (KT=1)
        int r = i >> 12, rem = i & 4095;
        int ct8 = rem >> 9, m16 = (rem >> 5) & 15, q = (rem >> 3) & 3, j = rem & 7;
        int n = ct8 * 16 + m16, k = q * 8 + j;
        w1t[i] = (k < EMB) ? f2b(W1[(r << 11) + (k << 7) + n]) : (unsigned short)0;
        return;
    }
    i -= R_W1;
    if (i < R_R1) {
        int ct8 = i >> 9, m16 = (i >> 5) & 15, q = (i >> 3) & 3, j = i & 7;
        int n = ct8 * 16 + m16, k = q * 8 + j;
        r1t[i] = (k < EMB) ? f2b(root1[(k << 7) + n]) : (unsigned short)0;
        return;
    }
    i -= R_R1;
    if (i < R_R2) {
        int ct8 = i >> 11, ks = (i >> 9) & 3, m16 = (i >> 5) & 15, q = (i >> 3) & 3, j = i & 7;
        int n = ct8 * 16 + m16, k = ks * 32 + q * 8 + j;
        r2t[i] = f2b(root2[(k << 7) + n]);
        return;
    }
    i -= R_R2;
    if (i < R_HIST) atomicAdd(&hist[dst[i] * N_REL + et[i]], 1);
}

// ======== 2-level exclusive scan over NBP = 626 x 1024 (+ inv fused) ========
__global__ void scan1_k(const int* __restrict__ hist, int* __restrict__ binoff,
                        int* __restrict__ bsum, float* __restrict__ inv) {
    __shared__ int sh[256];
    const int t = threadIdx.x;
    const int base = blockIdx.x * 1024 + t * 4;
    int4 h4 = *(const int4*)(hist + base);
    float4 iv4;
    iv4.x = h4.x > 0 ? 1.0f / h4.x : 0.0f;
    iv4.y = h4.y > 0 ? 1.0f / h4.y : 0.0f;
    iv4.z = h4.z > 0 ? 1.0f / h4.z : 0.0f;
    iv4.w = h4.w > 0 ? 1.0f / h4.w : 0.0f;
    *(float4*)(inv + base) = iv4;
    int ts = h4.x + h4.y + h4.z + h4.w;
    sh[t] = ts;
    __syncthreads();
    for (int o = 1; o < 256; o <<= 1) {
        int v = (t >= o) ? sh[t - o] : 0;
        __syncthreads();
        sh[t] += v;
        __syncthreads();
    }
    int exc = sh[t] - ts;
    binoff[base + 0] = exc;
    binoff[base + 1] = exc + h4.x;
    binoff[base + 2] = exc + h4.x + h4.y;
    binoff[base + 3] = exc + h4.x + h4.y + h4.z;
    if (t == 255) bsum[blockIdx.x] = sh[255];
}

__global__ void scan2_k(const int* __restrict__ bsum, int* __restrict__ bbase) {
    __shared__ int sh[1024];
    const int t = threadIdx.x;
    int v = (t < NBP / 1024) ? bsum[t] : 0;
    sh[t] = v;
    __syncthreads();
    for (int o = 1; o < 1024; o <<= 1) {
        int u = (t >= o) ? sh[t - o] : 0;
        __syncthreads();
        sh[t] += u;
        __syncthreads();
    }
    if (t < NBP / 1024) bbase[t] = sh[t] - v;
}

__global__ void scan3_k(int* __restrict__ binoff, const int* __restrict__ bbase,
                        int* __restrict__ cursors) {
    int i = blockIdx.x * 256 + threadIdx.x;
    if (i < NBP) {
        int v = binoff[i] + bbase[i >> 10];
        binoff[i] = v;
        cursors[i] = v;
    }
    if (i == 0) binoff[NBP] = N_EDGES;
}

__global__ void scatter_k(const int* __restrict__ src, const int* __restrict__ dst,
                          const int* __restrict__ et, int* __restrict__ cursors,
                          int* __restrict__ ssrc) {
    int e = blockIdx.x * 256 + threadIdx.x;
    if (e < 4) ssrc[N_EDGES + e] = 0;   // pad: safe src for speculative loads
    if (e < N_EDGES) {
        int b = dst[e] * N_REL + et[e];
        int p = atomicAdd(&cursors[b], 1);
        ssrc[p] = src[e];
    }
}

// ======== fused aggregate+transform, relation-split, fp32 partials ========
// R17 structure scaled to 64-ROW BLOCKS (RT=4 row tiles): halves the number
// of block-iterations (the measured fixed-cost unit, ~2.2k cyc each)
// while doubling per-iteration work, which sits well below the floor.
// Gather: 64 rows x NCH chunks = 256 threads, one item each. Pad rows
// (>=N_NODES) have cnt=0 and inv=0 -> zero A rows; pad outputs land in the
// oversized part buffer and are never reduced.
template<int KT, int LSS, int CW, int RG, int RT>
__global__ __launch_bounds__(256) void gemm_f(
    const int* __restrict__ binoff, const float* __restrict__ inv,
    const int* __restrict__ ssrc,
    const unsigned short* __restrict__ G,    // bf16 rows [*, KT*32]
    const unsigned short* __restrict__ Bw,   // bf16 frag-major [r][ct8][ks][512]
    const unsigned short* __restrict__ Br,   // bf16 frag-major [ct8][ks][512]
    float* __restrict__ part) {

    constexpr int ROW = KT * 32;
    constexpr int NROWS = 16 * RT;
    constexpr int NCH = ROW / CW;
    constexpr int CP8 = CW / 8;
    static_assert(NCH * CW == ROW, "chunk covering must be exact");
    static_assert(NROWS * NCH == 256, "one gather item per thread");

    __shared__ __align__(16) unsigned short As[2][NROWS * LSS];
    __shared__ int   smO[NROWS * (RG + 1)];
    __shared__ float smI[NROWS * RG];

    const int t = threadIdx.x;
    const int w = t >> 6, lane = t & 63;
    const int q = lane >> 4, m16 = lane & 15;
    const int d0 = blockIdx.x * NROWS;
    const int r0 = blockIdx.y * RG;
    const bool isLast = (blockIdx.y == gridDim.y - 1);
    const int colb = w * 32;
    const int cb16 = colb >> 4;                 // base coltile index
    const int fo = m16 * 32 + q * 8;            // lane offset within a 512-short fragment
    const int grow = t / NCH, gcc = t % NCH;
    const int mb  = grow * (RG + 1);
    const int mbI = grow * RG;

    // ---- meta preload (this group's bins only) ----
    for (int i = t; i < NROWS * (RG + 1); i += 256) {
        int row = i / (RG + 1), rr = i % (RG + 1);
        smO[i] = binoff[(d0 + row) * N_REL + r0 + rr];
    }
    for (int i = t; i < NROWS * RG; i += 256) {
        int row = i / RG, rr = i % RG;
        smI[i] = inv[(d0 + row) * N_REL + r0 + rr];
    }
    lds_barrier();

    f4v acc[RT][2];
#pragma unroll
    for (int rt = 0; rt < RT; ++rt)
#pragma unroll
        for (int ct = 0; ct < 2; ++ct) acc[rt][ct] = f4v{0.f, 0.f, 0.f, 0.f};

    // ---- staged-edge pipeline state ----
    us8v gE[4][CP8];
#pragma unroll
    for (int e = 0; e < 4; ++e)
#pragma unroll
        for (int j = 0; j < CP8; ++j) gE[e][j] = us8v{};
    int sx[4] = {0, 0, 0, 0};

    {
        const int so = smO[mb], cnt = smO[mb + 1] - so;
        int s0 = ssrc[so], s1 = ssrc[so + 1], s2 = ssrc[so + 2], s3 = ssrc[so + 3]; // pad-safe
        if (cnt >= 1) {
            const unsigned short* gp = G + (size_t)s0 * ROW + gcc * CW;
#pragma unroll
            for (int j = 0; j < CP8; ++j) gE[0][j] = *(const us8v*)(gp + j * 8);
        }
        if (cnt >= 2) {
            const unsigned short* gp = G + (size_t)s1 * ROW + gcc * CW;
#pragma unroll
            for (int j = 0; j < CP8; ++j) gE[1][j] = *(const us8v*)(gp + j * 8);
        }
        if (cnt >= 3) {
            const unsigned short* gp = G + (size_t)s2 * ROW + gcc * CW;
#pragma unroll
            for (int j = 0; j < CP8; ++j) gE[2][j] = *(const us8v*)(gp + j * 8);
        }
        if (cnt >= 4) {
            const unsigned short* gp = G + (size_t)s3 * ROW + gcc * CW;
#pragma unroll
            for (int j = 0; j < CP8; ++j) gE[3][j] = *(const us8v*)(gp + j * 8);
        }
        if (RG > 1) {
            const int so1 = smO[mb + 1];
            sx[0] = ssrc[so1]; sx[1] = ssrc[so1 + 1];
            sx[2] = ssrc[so1 + 2]; sx[3] = ssrc[so1 + 3];
        }
    }

    // B fragments for it=0 (fragment-major: contiguous 1 KB per load)
    bf8v bfr[2][KT];
#pragma unroll
    for (int ct = 0; ct < 2; ++ct) {
#pragma unroll
        for (int ks = 0; ks < KT; ++ks)
            bfr[ct][ks] = *(const bf8v*)(Bw + (size_t)r0 * (HID * ROW)
                              + ((cb16 + ct) * KT + ks) * 512 + fo);
    }

    for (int it = 0; it < RG; ++it) {
        unsigned short* Ab = As[it & 1];
        // ---- gather (consumes staged edges) + pre-barrier prefetch issue ----
        {
            const int so = smO[mb + it], eo = smO[mb + it + 1];
            const int cnt = eo - so;
            const float m2 = cnt >= 2 ? 1.f : 0.f;
            const float m3 = cnt >= 3 ? 1.f : 0.f;
            const float m4 = cnt >= 4 ? 1.f : 0.f;
            float a[CW];
#pragma unroll
            for (int j = 0; j < CP8; ++j)
#pragma unroll
                for (int k = 0; k < 8; ++k)
                    a[j * 8 + k] = b2f(gE[0][j][k]) + m2 * b2f(gE[1][j][k])
                                 + m3 * b2f(gE[2][j][k]) + m4 * b2f(gE[3][j][k]);
            for (int p = so + 4; p < eo; ++p) {     // rare tail (P ~2e-3)
                const unsigned short* gp = G + (size_t)ssrc[p] * ROW + gcc * CW;
#pragma unroll
                for (int j = 0; j < CP8; ++j) {
                    us8v g = *(const us8v*)(gp + j * 8);
#pragma unroll
                    for (int k = 0; k < 8; ++k) a[j * 8 + k] += b2f(g[k]);
                }
            }
            const float iv = smI[mbI + it];
            unsigned short* wp = &Ab[grow * LSS + gcc * CW];
#pragma unroll
            for (int j = 0; j < CP8; ++j) {
                us8v sv;
#pragma unroll
                for (int k = 0; k < 8; ++k) sv[k] = f2b(a[j * 8 + k] * iv);
                *(us8v*)(wp + j * 8) = sv;
            }

            // pre-barrier: issue it+1's staged edges + srcs for it+2
            if (it + 1 < RG) {
                const int c1 = smO[mb + it + 2] - smO[mb + it + 1];
                if (c1 >= 1) {
                    const unsigned short* gp = G + (size_t)sx[0] * ROW + gcc * CW;
#pragma unroll
                    for (int j = 0; j < CP8; ++j) gE[0][j] = *(const us8v*)(gp + j * 8);
                }
                if (c1 >= 2) {
                    const unsigned short* gp = G + (size_t)sx[1] * ROW + gcc * CW;
#pragma unroll
                    for (int j = 0; j < CP8; ++j) gE[1][j] = *(const us8v*)(gp + j * 8);
                }
                if (c1 >= 3) {
                    const unsigned short* gp = G + (size_t)sx[2] * ROW + gcc * CW;
#pragma unroll
                    for (int j = 0; j < CP8; ++j) gE[2][j] = *(const us8v*)(gp + j * 8);
                }
                if (c1 >= 4) {
                    const unsigned short* gp = G + (size_t)sx[3] * ROW + gcc * CW;
#pragma unroll
                    for (int j = 0; j < CP8; ++j) gE[3][j] = *(const us8v*)(gp + j * 8);
                }
                if (it + 2 < RG) {
                    const int so2 = smO[mb + it + 2];
                    sx[0] = ssrc[so2]; sx[1] = ssrc[so2 + 1];
                    sx[2] = ssrc[so2 + 2]; sx[3] = ssrc[so2 + 3];
                }
            }
        }
        lds_barrier();   // LDS-only drain: global prefetches stay in flight

        // ---- A fragments + MFMA ----
#pragma unroll
        for (int rt = 0; rt < RT; ++rt) {
            const unsigned short* ar = &Ab[(m16 + 16 * rt) * LSS];
#pragma unroll
            for (int ks = 0; ks < KT; ++ks) {
                bf8v af = *(const bf8v*)(ar + ks * 32 + q * 8);
                acc[rt][0] = __builtin_amdgcn_mfma_f32_16x16x32_bf16(af, bfr[0][ks], acc[rt][0], 0, 0, 0);
                acc[rt][1] = __builtin_amdgcn_mfma_f32_16x16x32_bf16(af, bfr[1][ks], acc[rt][1], 0, 0, 0);
            }
        }

        // ---- B fragments for it+1 (root weights after last relation of last group) ----
        const unsigned short* Bp = (it + 1 < RG) ? (Bw + (size_t)(r0 + it + 1) * (HID * ROW))
                                                 : (isLast ? Br : nullptr);
        if (Bp) {
#pragma unroll
            for (int ct = 0; ct < 2; ++ct) {
#pragma unroll
                for (int ks = 0; ks < KT; ++ks)
                    bfr[ct][ks] = *(const bf8v*)(Bp + ((cb16 + ct) * KT + ks) * 512 + fo);
            }
        }
    }

    // ---- root transform (last group only): A straight from global ----
    if (isLast) {
#pragma unroll
        for (int rt = 0; rt < RT; ++rt) {
#pragma unroll
            for (int ks = 0; ks < KT; ++ks) {
                bf8v af = *(const bf8v*)(G + (size_t)(d0 + m16 + 16 * rt) * ROW + ks * 32 + q * 8);
                acc[rt][0] = __builtin_amdgcn_mfma_f32_16x16x32_bf16(af, bfr[0][ks], acc[rt][0], 0, 0, 0);
                acc[rt][1] = __builtin_amdgcn_mfma_f32_16x16x32_bf16(af, bfr[1][ks], acc[rt][1], 0, 0, 0);
            }
        }
    }

    // ---- epilogue: NONTEMPORAL fp32 partial stores (keep L2 for G/B) ----
    float* pb = part + (size_t)blockIdx.y * NP * HID;
#pragma unroll
    for (int ct = 0; ct < 2; ++ct) {
        const int col = colb + 16 * ct + m16;
#pragma unroll
        for (int rt = 0; rt < RT; ++rt) {
#pragma unroll
            for (int g = 0; g < 4; ++g) {
                const int rr = 16 * rt + q * 4 + g;
                __builtin_nontemporal_store(acc[rt][ct][g],
                    &pb[(size_t)(d0 + rr) * HID + col]);
            }
        }
    }
}

// ======== reduces (nontemporal partial loads; real rows only) ========
__global__ __launch_bounds__(256) void reduce1_k(
    const float* __restrict__ part, const float* __restrict__ b1,
    unsigned short* __restrict__ h1b) {
    int i = blockIdx.x * 256 + threadIdx.x;   // float4 index
    if (i >= N_NODES * HID / 4) return;
    const size_t S = (size_t)NP * HID;
    float4 bb = *(const float4*)(b1 + ((i * 4) & 127));
    float r0 = bb.x, r1 = bb.y, r2 = bb.z, r3 = bb.w;
#pragma unroll
    for (int p = 0; p < 2; ++p) {
        const float* pp = part + p * S + (size_t)i * 4;
        r0 += __builtin_nontemporal_load(pp + 0);
        r1 += __builtin_nontemporal_load(pp + 1);
        r2 += __builtin_nontemporal_load(pp + 2);
        r3 += __builtin_nontemporal_load(pp + 3);
    }
    us4v v;
    v[0] = f2b(fmaxf(r0, 0.0f));
    v[1] = f2b(fmaxf(r1, 0.0f));
    v[2] = f2b(fmaxf(r2, 0.0f));
    v[3] = f2b(fmaxf(r3, 0.0f));
    *(us4v*)(h1b + (size_t)i * 4) = v;
}

__global__ __launch_bounds__(256) void reduce2_k(
    const float* __restrict__ part, const float* __restrict__ b2,
    float* __restrict__ out) {
    int i = blockIdx.x * 256 + threadIdx.x;   // float4 index
    if (i >= N_NODES * HID / 4) return;
    const size_t S = (size_t)NP * HID;
    float4 bb = *(const float4*)(b2 + ((i * 4) & 127));
    float r0 = bb.x, r1 = bb.y, r2 = bb.z, r3 = bb.w;
#pragma unroll
    for (int p = 0; p < 4; ++p) {
        const float* pp = part + p * S + (size_t)i * 4;
        r0 += __builtin_nontemporal_load(pp + 0);
        r1 += __builtin_nontemporal_load(pp + 1);
        r2 += __builtin_nontemporal_load(pp + 2);
        r3 += __builtin_nontemporal_load(pp + 3);
    }
    float4 r; r.x = r0; r.y = r1; r.z = r2; r.w = r3;
    ((float4*)out)[i] = r;
}

extern "C" void kernel_launch(void* const* d_in, const int* in_sizes, int n_in,
                              void* d_out, int out_size, void* d_ws, size_t ws_size,
                              hipStream_t stream) {
    const int*   ei    = (const int*)d_in[0];   // [2, E]
    const int*   et    = (const int*)d_in[1];   // [E]
    const float* x     = (const float*)d_in[2]; // [N, 16]
    const float* W1    = (const float*)d_in[3]; // [32, 16, 128]
    const float* root1 = (const float*)d_in[4]; // [16, 128]
    const float* b1    = (const float*)d_in[5]; // [128]
    const float* W2    = (const float*)d_in[6]; // [32, 128, 128]
    const float* root2 = (const float*)d_in[7]; // [128, 128]
    const float* b2    = (const float*)d_in[8]; // [128]
    float* out = (float*)d_out;

    // ---- workspace layout (~65 MB) ----
    char* ws = (char*)d_ws;
    size_t off = 0;
    auto alloc = [&](size_t bytes) { void* p = ws + off; off = (off + bytes + 63) & ~(size_t)63; return p; };
    int*   hist    = (int*)  alloc((size_t)NBP * 4);
    int*   binoff  = (int*)  alloc((size_t)(NBP + 1) * 4);
    int*   cursors = (int*)  alloc((size_t)NBP * 4);
    float* inv     = (float*)alloc((size_t)NBP * 4);
    int*   bsum    = (int*)  alloc((NBP / 1024) * 4);
    int*   bbase   = (int*)  alloc((NBP / 1024) * 4);
    int*   ssrc    = (int*)  alloc((size_t)(N_EDGES + 4) * 4);
    unsigned short* xb  = (unsigned short*)alloc((size_t)NP * 32 * 2);
    unsigned short* h1b = (unsigned short*)alloc((size_t)NP * HID * 2);
    unsigned short* w1t = (unsigned short*)alloc((size_t)N_REL * HID * 32 * 2);
    unsigned short* r1t = (unsigned short*)alloc((size_t)HID * 32 * 2);
    unsigned short* w2t = (unsigned short*)alloc((size_t)N_REL * HID * HID * 2);
    unsigned short* r2t = (unsigned short*)alloc((size_t)HID * HID * 2);
    float* part = (float*)alloc((size_t)4 * NP * HID * 4);   // 4 partials, reused both layers

    const int* src = ei;
    const int* dst = ei + N_EDGES;

    hipMemsetAsync(hist, 0, (size_t)NBP * 4, stream);
    pre1_k<<<(PRE_TOT + 255) / 256, 256, 0, stream>>>(
        dst, et, x, W1, root1, W2, root2, hist, xb, w1t, r1t, w2t, r2t);
    scan1_k<<<NBP / 1024, 256, 0, stream>>>(hist, binoff, bsum, inv);
    scan2_k<<<1, 1024, 0, stream>>>(bsum, bbase);
    scan3_k<<<(NBP + 255) / 256, 256, 0, stream>>>(binoff, bbase, cursors);
    scatter_k<<<(N_EDGES + 255) / 256, 256, 0, stream>>>(src, dst, et, cursors, ssrc);

    // ---- layer 1: 64-row blocks, 2 relation groups (16 rels; last adds root) ----
    gemm_f<1, 40, 8, 16, 4><<<dim3(NP / 64, 2), 256, 0, stream>>>(
        binoff, inv, ssrc, xb, w1t, r1t, part);
    reduce1_k<<<(N_NODES * HID / 4 + 255) / 256, 256, 0, stream>>>(part, b1, h1b);

    // ---- layer 2: 64-row blocks, 4 relation groups (8 rels; last adds root) ----
    gemm_f<4, 136, 32, 8, 4><<<dim3(NP / 64, 4), 256, 0, stream>>>(
        binoff, inv, ssrc, h1b, w2t, r2t, part);
    reduce2_k<<<(N_NODES * HID / 4 + 255) / 256, 256, 0, stream>>>(part, b2, out);
}

// Round 20
// 246.477 us; speedup vs baseline: 1.0215x; 1.0215x over previous
//
#include <hip/hip_runtime.h>
#include <hip/hip_bf16.h>

#define N_NODES 20000
#define N_REL 32
#define HID 128
#define EMB 16
#define N_EDGES 600000
#define NB (N_NODES * N_REL)   // 640000 bins

typedef __attribute__((ext_vector_type(8))) short  bf8v;   // 8 bf16 (MFMA A/B frag)
typedef __attribute__((ext_vector_type(8))) unsigned short us8v; // 16-byte unit
typedef __attribute__((ext_vector_type(4))) unsigned short us4v; // 8-byte unit
typedef __attribute__((ext_vector_type(4))) float  f4v;    // MFMA C/D frag

__device__ __forceinline__ unsigned short f2b(float f) {
    __hip_bfloat16 h = __float2bfloat16(f);
    return __builtin_bit_cast(unsigned short, h);
}
__device__ __forceinline__ float b2f(unsigned short u) {
    unsigned int x = ((unsigned int)u) << 16;
    return __builtin_bit_cast(float, x);
}

// Barrier with LDS-only drain (global prefetches stay in flight).
__device__ __forceinline__ void lds_barrier() {
    asm volatile("s_waitcnt lgkmcnt(0)\n\ts_barrier" ::: "memory");
}

// ======== pre-pass: histogram + fragment-major bf16 weight layouts ========
// Weight layout (fragment-major): B[r][ct8][ks][m16][q][j8] — a wave's
// fragment load (lanes (q,m16)) covers one CONTIGUOUS 1 KB block.
#define R_W2 (N_REL * HID * HID)        // 1048576
#define R_XB (N_NODES * 32)             // 640000
#define R_W1 (N_REL * HID * 32)         // 131072
#define R_R1 (HID * 32)                 // 4096
#define R_R2 (HID * HID)                // 16384
#define R_HIST N_EDGES                  // 600000
#define PRE_TOT (R_W2 + R_XB + R_W1 + R_R1 + R_R2 + R_HIST)

__global__ __launch_bounds__(256) void pre1_k(
    const int* __restrict__ dst, const int* __restrict__ et,
    const float* __restrict__ x, const float* __restrict__ W1,
    const float* __restrict__ root1, const float* __restrict__ W2,
    const float* __restrict__ root2,
    int* __restrict__ hist,
    unsigned short* __restrict__ xb, unsigned short* __restrict__ w1t,
    unsigned short* __restrict__ r1t, unsigned short* __restrict__ w2t,
    unsigned short* __restrict__ r2t) {
    int i = blockIdx.x * 256 + threadIdx.x;
    if (i < R_W2) {
        // coalesced read of W2 [r][k][n]; fragment-major write (KT=4)
        int r = i >> 14, k = (i >> 7) & 127, n = i & 127;
        int ct8 = n >> 4, m16 = n & 15, ks = k >> 5, q = (k >> 3) & 3, j = k & 7;
        w2t[(size_t)r * 16384 + (ct8 * 4 + ks) * 512 + m16 * 32 + q * 8 + j] = f2b(W2[i]);
        return;
    }
    i -= R_W2;
    if (i < R_XB) {
        int n = i >> 5, k = i & 31;
        xb[i] = (k < EMB) ? f2b(x[n * EMB + k]) : (unsigned short)0;
        return;
    }
    i -= R_XB;
    if (i < R_W1) {
        // dst-linear fragment-major (KT=1)
        int r = i >> 12, rem = i & 4095;
        int ct8 = rem >> 9, m16 = (rem >> 5) & 15, q = (rem >> 3) & 3, j = rem & 7;
        int n = ct8 * 16 + m16, k = q * 8 + j;
        w1t[i] = (k < EMB) ? f2b(W1[(r << 11) + (k << 7) + n]) : (unsigned short)0;
        return;
    }
    i -= R_W1;
    if (i < R_R1) {
        int ct8 = i >> 9, m16 = (i >> 5) & 15, q = (i >> 3) & 3, j = i & 7;
        int n = ct8 * 16 + m16, k = q * 8 + j;
        r1t[i] = (k < EMB) ? f2b(root1[(k << 7) + n]) : (unsigned short)0;
        return;
    }
    i -= R_R1;
    if (i < R_R2) {
        int ct8 = i >> 11, ks = (i >> 9) & 3, m16 = (i >> 5) & 15, q = (i >> 3) & 3, j = i & 7;
        int n = ct8 * 16 + m16, k = ks * 32 + q * 8 + j;
        r2t[i] = f2b(root2[(k << 7) + n]);
        return;
    }
    i -= R_R2;
    if (i < R_HIST) atomicAdd(&hist[dst[i] * N_REL + et[i]], 1);
}

// ======== 2-level exclusive scan over NB = 625 x 1024 (+ inv fused) ========
__global__ void scan1_k(const int* __restrict__ hist, int* __restrict__ binoff,
                        int* __restrict__ bsum, float* __restrict__ inv) {
    __shared__ int sh[256];
    const int t = threadIdx.x;
    const int base = blockIdx.x * 1024 + t * 4;
    int4 h4 = *(const int4*)(hist + base);
    float4 iv4;
    iv4.x = h4.x > 0 ? 1.0f / h4.x : 0.0f;
    iv4.y = h4.y > 0 ? 1.0f / h4.y : 0.0f;
    iv4.z = h4.z > 0 ? 1.0f / h4.z : 0.0f;
    iv4.w = h4.w > 0 ? 1.0f / h4.w : 0.0f;
    *(float4*)(inv + base) = iv4;
    int ts = h4.x + h4.y + h4.z + h4.w;
    sh[t] = ts;
    __syncthreads();
    for (int o = 1; o < 256; o <<= 1) {
        int v = (t >= o) ? sh[t - o] : 0;
        __syncthreads();
        sh[t] += v;
        __syncthreads();
    }
    int exc = sh[t] - ts;
    binoff[base + 0] = exc;
    binoff[base + 1] = exc + h4.x;
    binoff[base + 2] = exc + h4.x + h4.y;
    binoff[base + 3] = exc + h4.x + h4.y + h4.z;
    if (t == 255) bsum[blockIdx.x] = sh[255];
}

__global__ void scan2_k(const int* __restrict__ bsum, int* __restrict__ bbase) {
    __shared__ int sh[1024];
    const int t = threadIdx.x;
    int v = (t < 625) ? bsum[t] : 0;
    sh[t] = v;
    __syncthreads();
    for (int o = 1; o < 1024; o <<= 1) {
        int u = (t >= o) ? sh[t - o] : 0;
        __syncthreads();
        sh[t] += u;
        __syncthreads();
    }
    if (t < 625) bbase[t] = sh[t] - v;
}

__global__ void scan3_k(int* __restrict__ binoff, const int* __restrict__ bbase,
                        int* __restrict__ cursors) {
    int i = blockIdx.x * 256 + threadIdx.x;
    if (i < NB) {
        int v = binoff[i] + bbase[i >> 10];
        binoff[i] = v;
        cursors[i] = v;
    }
    if (i == 0) binoff[NB] = N_EDGES;
}

__global__ void scatter_k(const int* __restrict__ src, const int* __restrict__ dst,
                          const int* __restrict__ et, int* __restrict__ cursors,
                          int* __restrict__ ssrc) {
    int e = blockIdx.x * 256 + threadIdx.x;
    if (e < 4) ssrc[N_EDGES + e] = 0;   // pad: safe src for speculative loads
    if (e < N_EDGES) {
        int b = dst[e] * N_REL + et[e];
        int p = atomicAdd(&cursors[b], 1);
        ssrc[p] = src[e];
    }
}

// ======== fused aggregate+transform, relation-split, fp32 partials ========
// R17 structure (best measured) + GATHER UNIT-INTERLEAVE: a thread's CP8
// 16-byte loads cover row units (gcc + j*NCH) instead of (gcc*CP8 + j), so
// each staged-load wave-instruction reads a CONTIGUOUS 128 B span of every
// row it touches — 16 lines/instr touched once (the minimum) instead of 32
// lines touched twice. Same lever (TA line-work) as R17's frag-major B win.
// LDS layout stays canonical because loads and stores use the same unit.
template<int KT, int LSS, int CW, int RG>
__global__ __launch_bounds__(256) void gemm_f(
    const int* __restrict__ binoff, const float* __restrict__ inv,
    const int* __restrict__ ssrc,
    const unsigned short* __restrict__ G,    // bf16 rows [*, KT*32]
    const unsigned short* __restrict__ Bw,   // bf16 frag-major [r][ct8][ks][512]
    const unsigned short* __restrict__ Br,   // bf16 frag-major [ct8][ks][512]
    float* __restrict__ part) {

    constexpr int ROW = KT * 32;
    constexpr int NCH = ROW / CW;
    constexpr int CP8 = CW / 8;
    static_assert(NCH * CW == ROW, "chunk covering must be exact");
    static_assert(32 * NCH <= 256, "one gather item per thread");

    __shared__ __align__(16) unsigned short As[2][32 * LSS];
    __shared__ int   smO[32 * (RG + 1)];
    __shared__ float smI[32 * RG];

    const int t = threadIdx.x;
    const int w = t >> 6, lane = t & 63;
    const int q = lane >> 4, m16 = lane & 15;
    const int d0 = blockIdx.x * 32;
    const int r0 = blockIdx.y * RG;
    const bool isLast = (blockIdx.y == gridDim.y - 1);
    const int colb = w * 32;
    const int cb16 = colb >> 4;                 // base coltile index
    const int fo = m16 * 32 + q * 8;            // lane offset within a 512-short fragment
    const bool gat = t < 32 * NCH;
    const int grow = t / NCH, gcc = t % NCH;
    const int mb  = grow * (RG + 1);
    const int mbI = grow * RG;
    // unit offsets (shorts) for this thread's CP8 16-byte units
    int uo[CP8];
#pragma unroll
    for (int j = 0; j < CP8; ++j) uo[j] = (gcc + j * NCH) * 8;

    // ---- meta preload (this group's bins only) ----
    for (int i = t; i < 32 * (RG + 1); i += 256) {
        int row = i / (RG + 1), rr = i % (RG + 1);
        smO[i] = binoff[(d0 + row) * N_REL + r0 + rr];
    }
    for (int i = t; i < 32 * RG; i += 256) {
        int row = i / RG, rr = i % RG;
        smI[i] = inv[(d0 + row) * N_REL + r0 + rr];
    }
    lds_barrier();

    f4v acc[2][2];
#pragma unroll
    for (int rt = 0; rt < 2; ++rt)
#pragma unroll
        for (int ct = 0; ct < 2; ++ct) acc[rt][ct] = f4v{0.f, 0.f, 0.f, 0.f};

    // ---- staged-edge pipeline state ----
    us8v gE[4][CP8];
#pragma unroll
    for (int e = 0; e < 4; ++e)
#pragma unroll
        for (int j = 0; j < CP8; ++j) gE[e][j] = us8v{};
    int sx[4] = {0, 0, 0, 0};

    if (gat) {
        const int so = smO[mb], cnt = smO[mb + 1] - so;
        int s0 = ssrc[so], s1 = ssrc[so + 1], s2 = ssrc[so + 2], s3 = ssrc[so + 3]; // pad-safe
        if (cnt >= 1) {
            const unsigned short* gp = G + (size_t)s0 * ROW;
#pragma unroll
            for (int j = 0; j < CP8; ++j) gE[0][j] = *(const us8v*)(gp + uo[j]);
        }
        if (cnt >= 2) {
            const unsigned short* gp = G + (size_t)s1 * ROW;
#pragma unroll
            for (int j = 0; j < CP8; ++j) gE[1][j] = *(const us8v*)(gp + uo[j]);
        }
        if (cnt >= 3) {
            const unsigned short* gp = G + (size_t)s2 * ROW;
#pragma unroll
            for (int j = 0; j < CP8; ++j) gE[2][j] = *(const us8v*)(gp + uo[j]);
        }
        if (cnt >= 4) {
            const unsigned short* gp = G + (size_t)s3 * ROW;
#pragma unroll
            for (int j = 0; j < CP8; ++j) gE[3][j] = *(const us8v*)(gp + uo[j]);
        }
        if (RG > 1) {
            const int so1 = smO[mb + 1];
            sx[0] = ssrc[so1]; sx[1] = ssrc[so1 + 1];
            sx[2] = ssrc[so1 + 2]; sx[3] = ssrc[so1 + 3];
        }
    }

    // B fragments for it=0 (fragment-major: contiguous 1 KB per load)
    bf8v bfr[2][KT];
#pragma unroll
    for (int ct = 0; ct < 2; ++ct) {
#pragma unroll
        for (int ks = 0; ks < KT; ++ks)
            bfr[ct][ks] = *(const bf8v*)(Bw + (size_t)r0 * (HID * ROW)
                              + ((cb16 + ct) * KT + ks) * 512 + fo);
    }

    for (int it = 0; it < RG; ++it) {
        unsigned short* Ab = As[it & 1];
        // ---- gather (consumes staged edges) + pre-barrier prefetch issue ----
        if (gat) {
            const int so = smO[mb + it], eo = smO[mb + it + 1];
            const int cnt = eo - so;
            const float m2 = cnt >= 2 ? 1.f : 0.f;
            const float m3 = cnt >= 3 ? 1.f : 0.f;
            const float m4 = cnt >= 4 ? 1.f : 0.f;
            float a[CW];
#pragma unroll
            for (int j = 0; j < CP8; ++j)
#pragma unroll
                for (int k = 0; k < 8; ++k)
                    a[j * 8 + k] = b2f(gE[0][j][k]) + m2 * b2f(gE[1][j][k])
                                 + m3 * b2f(gE[2][j][k]) + m4 * b2f(gE[3][j][k]);
            for (int p = so + 4; p < eo; ++p) {     // rare tail (P ~2e-3)
                const unsigned short* gp = G + (size_t)ssrc[p] * ROW;
#pragma unroll
                for (int j = 0; j < CP8; ++j) {
                    us8v g = *(const us8v*)(gp + uo[j]);
#pragma unroll
                    for (int k = 0; k < 8; ++k) a[j * 8 + k] += b2f(g[k]);
                }
            }
            const float iv = smI[mbI + it];
            unsigned short* wp = &Ab[grow * LSS];
#pragma unroll
            for (int j = 0; j < CP8; ++j) {
                us8v sv;
#pragma unroll
                for (int k = 0; k < 8; ++k) sv[k] = f2b(a[j * 8 + k] * iv);
                *(us8v*)(wp + uo[j]) = sv;
            }

            // pre-barrier: issue it+1's staged edges + srcs for it+2
            if (it + 1 < RG) {
                const int c1 = smO[mb + it + 2] - smO[mb + it + 1];
                if (c1 >= 1) {
                    const unsigned short* gp = G + (size_t)sx[0] * ROW;
#pragma unroll
                    for (int j = 0; j < CP8; ++j) gE[0][j] = *(const us8v*)(gp + uo[j]);
                }
                if (c1 >= 2) {
                    const unsigned short* gp = G + (size_t)sx[1] * ROW;
#pragma unroll
                    for (int j = 0; j < CP8; ++j) gE[1][j] = *(const us8v*)(gp + uo[j]);
                }
                if (c1 >= 3) {
                    const unsigned short* gp = G + (size_t)sx[2] * ROW;
#pragma unroll
                    for (int j = 0; j < CP8; ++j) gE[2][j] = *(const us8v*)(gp + uo[j]);
                }
                if (c1 >= 4) {
                    const unsigned short* gp = G + (size_t)sx[3] * ROW;
#pragma unroll
                    for (int j = 0; j < CP8; ++j) gE[3][j] = *(const us8v*)(gp + uo[j]);
                }
                if (it + 2 < RG) {
                    const int so2 = smO[mb + it + 2];
                    sx[0] = ssrc[so2]; sx[1] = ssrc[so2 + 1];
                    sx[2] = ssrc[so2 + 2]; sx[3] = ssrc[so2 + 3];
                }
            }
        }
        lds_barrier();   // LDS-only drain: global prefetches stay in flight

        // ---- A fragments + MFMA ----
#pragma unroll
        for (int rt = 0; rt < 2; ++rt) {
            const unsigned short* ar = &Ab[(m16 + 16 * rt) * LSS];
#pragma unroll
            for (int ks = 0; ks < KT; ++ks) {
                bf8v af = *(const bf8v*)(ar + ks * 32 + q * 8);
                acc[rt][0] = __builtin_amdgcn_mfma_f32_16x16x32_bf16(af, bfr[0][ks], acc[rt][0], 0, 0, 0);
                acc[rt][1] = __builtin_amdgcn_mfma_f32_16x16x32_bf16(af, bfr[1][ks], acc[rt][1], 0, 0, 0);
            }
        }

        // ---- B fragments for it+1 (root weights after last relation of last group) ----
        const unsigned short* Bp = (it + 1 < RG) ? (Bw + (size_t)(r0 + it + 1) * (HID * ROW))
                                                 : (isLast ? Br : nullptr);
        if (Bp) {
#pragma unroll
            for (int ct = 0; ct < 2; ++ct) {
#pragma unroll
                for (int ks = 0; ks < KT; ++ks)
                    bfr[ct][ks] = *(const bf8v*)(Bp + ((cb16 + ct) * KT + ks) * 512 + fo);
            }
        }
    }

    // ---- root transform (last group only): A straight from global ----
    if (isLast) {
#pragma unroll
        for (int rt = 0; rt < 2; ++rt) {
#pragma unroll
            for (int ks = 0; ks < KT; ++ks) {
                bf8v af = *(const bf8v*)(G + (size_t)(d0 + m16 + 16 * rt) * ROW + ks * 32 + q * 8);
                acc[rt][0] = __builtin_amdgcn_mfma_f32_16x16x32_bf16(af, bfr[0][ks], acc[rt][0], 0, 0, 0);
                acc[rt][1] = __builtin_amdgcn_mfma_f32_16x16x32_bf16(af, bfr[1][ks], acc[rt][1], 0, 0, 0);
            }
        }
    }

    // ---- epilogue: NONTEMPORAL fp32 partial stores (keep L2 for G/B) ----
    float* pb = part + (size_t)blockIdx.y * N_NODES * HID;
#pragma unroll
    for (int ct = 0; ct < 2; ++ct) {
        const int col = colb + 16 * ct + m16;
#pragma unroll
        for (int rt = 0; rt < 2; ++rt) {
#pragma unroll
            for (int g = 0; g < 4; ++g) {
                const int rr = 16 * rt + q * 4 + g;
                __builtin_nontemporal_store(acc[rt][ct][g],
                    &pb[(size_t)(d0 + rr) * HID + col]);
            }
        }
    }
}

// ======== reduces (nontemporal partial loads) ========
__global__ __launch_bounds__(256) void reduce1_k(
    const float* __restrict__ part, const float* __restrict__ b1,
    unsigned short* __restrict__ h1b) {
    int i = blockIdx.x * 256 + threadIdx.x;   // float4 index
    if (i >= N_NODES * HID / 4) return;
    const size_t S = (size_t)N_NODES * HID;
    float4 bb = *(const float4*)(b1 + ((i * 4) & 127));
    float r0 = bb.x, r1 = bb.y, r2 = bb.z, r3 = bb.w;
#pragma unroll
    for (int p = 0; p < 2; ++p) {
        const float* pp = part + p * S + (size_t)i * 4;
        r0 += __builtin_nontemporal_load(pp + 0);
        r1 += __builtin_nontemporal_load(pp + 1);
        r2 += __builtin_nontemporal_load(pp + 2);
        r3 += __builtin_nontemporal_load(pp + 3);
    }
    us4v v;
    v[0] = f2b(fmaxf(r0, 0.0f));
    v[1] = f2b(fmaxf(r1, 0.0f));
    v[2] = f2b(fmaxf(r2, 0.0f));
    v[3] = f2b(fmaxf(r3, 0.0f));
    *(us4v*)(h1b + (size_t)i * 4) = v;
}

__global__ __launch_bounds__(256) void reduce2_k(
    const float* __restrict__ part, const float* __restrict__ b2,
    float* __restrict__ out) {
    int i = blockIdx.x * 256 + threadIdx.x;   // float4 index
    if (i >= N_NODES * HID / 4) return;
    const size_t S = (size_t)N_NODES * HID;
    float4 bb = *(const float4*)(b2 + ((i * 4) & 127));
    float r0 = bb.x, r1 = bb.y, r2 = bb.z, r3 = bb.w;
#pragma unroll
    for (int p = 0; p < 4; ++p) {
        const float* pp = part + p * S + (size_t)i * 4;
        r0 += __builtin_nontemporal_load(pp + 0);
        r1 += __builtin_nontemporal_load(pp + 1);
        r2 += __builtin_nontemporal_load(pp + 2);
        r3 += __builtin_nontemporal_load(pp + 3);
    }
    float4 r; r.x = r0; r.y = r1; r.z = r2; r.w = r3;
    ((float4*)out)[i] = r;
}

extern "C" void kernel_launch(void* const* d_in, const int* in_sizes, int n_in,
                              void* d_out, int out_size, void* d_ws, size_t ws_size,
                              hipStream_t stream) {
    const int*   ei    = (const int*)d_in[0];   // [2, E]
    const int*   et    = (const int*)d_in[1];   // [E]
    const float* x     = (const float*)d_in[2]; // [N, 16]
    const float* W1    = (const float*)d_in[3]; // [32, 16, 128]
    const float* root1 = (const float*)d_in[4]; // [16, 128]
    const float* b1    = (const float*)d_in[5]; // [128]
    const float* W2    = (const float*)d_in[6]; // [32, 128, 128]
    const float* root2 = (const float*)d_in[7]; // [128, 128]
    const float* b2    = (const float*)d_in[8]; // [128]
    float* out = (float*)d_out;

    // ---- workspace layout (~60 MB) ----
    char* ws = (char*)d_ws;
    size_t off = 0;
    auto alloc = [&](size_t bytes) { void* p = ws + off; off = (off + bytes + 63) & ~(size_t)63; return p; };
    int*   hist    = (int*)  alloc((size_t)NB * 4);
    int*   binoff  = (int*)  alloc((size_t)(NB + 1) * 4);
    int*   cursors = (int*)  alloc((size_t)NB * 4);
    float* inv     = (float*)alloc((size_t)NB * 4);
    int*   bsum    = (int*)  alloc(625 * 4);
    int*   bbase   = (int*)  alloc(625 * 4);
    int*   ssrc    = (int*)  alloc((size_t)(N_EDGES + 4) * 4);
    unsigned short* xb  = (unsigned short*)alloc((size_t)N_NODES * 32 * 2);
    unsigned short* h1b = (unsigned short*)alloc((size_t)N_NODES * HID * 2);
    unsigned short* w1t = (unsigned short*)alloc((size_t)N_REL * HID * 32 * 2);
    unsigned short* r1t = (unsigned short*)alloc((size_t)HID * 32 * 2);
    unsigned short* w2t = (unsigned short*)alloc((size_t)N_REL * HID * HID * 2);
    unsigned short* r2t = (unsigned short*)alloc((size_t)HID * HID * 2);
    float* part = (float*)alloc((size_t)4 * N_NODES * HID * 4);   // 4 partials, reused both layers

    const int* src = ei;
    const int* dst = ei + N_EDGES;

    hipMemsetAsync(hist, 0, (size_t)NB * 4, stream);
    pre1_k<<<(PRE_TOT + 255) / 256, 256, 0, stream>>>(
        dst, et, x, W1, root1, W2, root2, hist, xb, w1t, r1t, w2t, r2t);
    scan1_k<<<NB / 1024, 256, 0, stream>>>(hist, binoff, bsum, inv);
    scan2_k<<<1, 1024, 0, stream>>>(bsum, bbase);
    scan3_k<<<(NB + 255) / 256, 256, 0, stream>>>(binoff, bbase, cursors);
    scatter_k<<<(N_EDGES + 255) / 256, 256, 0, stream>>>(src, dst, et, cursors, ssrc);

    // ---- layer 1: 2 relation groups (16 rels each; last adds root) ----
    gemm_f<1, 40, 8, 16><<<dim3(625, 2), 256, 0, stream>>>(
        binoff, inv, ssrc, xb, w1t, r1t, part);
    reduce1_k<<<(N_NODES * HID / 4 + 255) / 256, 256, 0, stream>>>(part, b1, h1b);

    // ---- layer 2: 4 relation groups (8 rels each; last adds root) ----
    gemm_f<4, 136, 16, 8><<<dim3(625, 4), 256, 0, stream>>>(
        binoff, inv, ssrc, h1b, w2t, r2t, part);
    reduce2_k<<<(N_NODES * HID / 4 + 255) / 256, 256, 0, stream>>>(part, b2, out);
}